// Round 9
// baseline (197.516 us; speedup 1.0000x reference)
//
#include <hip/hip_runtime.h>

#define Bb 64
#define Nn 1152
#define Oo 32
#define DOv 16
#define DIv 8
#define NG 4     // b's per thread; block = 4 waves x NG = 16 b's

// One routing iteration. NO LDS, NO BARRIERS: each lane streams its private
// W-slice (w[n][o][ih*8..ih*8+7][:] = 64 contiguous floats) through registers
// via 16 dwordx4 loads per n. x/vcum addresses are wave-uniform (broadcast
// loads). Waves drift independently; latency hides under other waves' FMA.
// Lane: o = t&31, ih = (t>>5)&1 (i-half), wave wv = t>>6 owns b = b0+g.
// vcum == nullptr -> uniform c = 1/32 (iteration 1).
template<int NC>
__global__ __launch_bounds__(256, 2) void caps_route(
    const float* __restrict__ x,     // [B, N, DI]
    const float* __restrict__ w,     // [N, O, DO, DI]
    const float* __restrict__ vcum,  // [B, O, DO] or nullptr
    float* __restrict__ spart)       // [nch, B, O, DO]
{
    const int t  = threadIdx.x;
    const int o  = t & 31;
    const int ih = (t >> 5) & 1;
    const int wv = t >> 6;                       // 0..3
    const int n0 = blockIdx.x * NC;
    const int b0 = blockIdx.y * (4 * NG) + wv * NG;   // wave-uniform

    const bool have_v = (vcum != nullptr);
    float vc[NG][8];
    if (have_v) {
#pragma unroll
        for (int g = 0; g < NG; ++g) {
            const float4* vp = (const float4*)(
                vcum + (((size_t)(b0 + g) * Oo + o) * DOv + ih * 8));
            float4 a = vp[0], b = vp[1];
            vc[g][0] = a.x; vc[g][1] = a.y; vc[g][2] = a.z; vc[g][3] = a.w;
            vc[g][4] = b.x; vc[g][5] = b.y; vc[g][6] = b.z; vc[g][7] = b.w;
        }
    }

    float sacc[NG][8];
#pragma unroll
    for (int g = 0; g < NG; ++g)
#pragma unroll
        for (int i = 0; i < 8; ++i) sacc[g][i] = 0.f;

    for (int nn = 0; nn < NC; ++nn) {
        const int n = n0 + nn;

        // this lane's W slice: 64 contiguous floats -> 16 float4 regs.
        // lanes of one o share 64B lines across k -> tile lands in L1 once.
        const float4* wp = (const float4*)(
            w + ((size_t)n * (Oo * DOv * DIv) + o * (DOv * DIv) + ih * 64));
        float4 wr[16];
#pragma unroll
        for (int k = 0; k < 16; ++k) wr[k] = wp[k];

        // x rows: wave-uniform addresses -> broadcast loads (1 line each)
        float xr[NG][8];
#pragma unroll
        for (int g = 0; g < NG; ++g) {
            const float4* xp = (const float4*)(
                x + ((size_t)(b0 + g) * Nn + n) * DIv);
            float4 a = xp[0], b = xp[1];
            xr[g][0] = a.x; xr[g][1] = a.y; xr[g][2] = a.z; xr[g][3] = a.w;
            xr[g][4] = b.x; xr[g][5] = b.y; xr[g][6] = b.z; xr[g][7] = b.w;
        }

        // xh[g][i] for global i = ih*8 + i  (fully summed over j: no combine
        // needed for sacc; logit needs one cross-half shfl)
        float xh[NG][8];
#pragma unroll
        for (int g = 0; g < NG; ++g)
#pragma unroll
            for (int i = 0; i < 8; ++i) xh[g][i] = 0.f;
#pragma unroll
        for (int i = 0; i < 8; ++i) {
            float4 w0 = wr[i * 2 + 0];   // j = 0..3
            float4 w1 = wr[i * 2 + 1];   // j = 4..7
#pragma unroll
            for (int g = 0; g < NG; ++g) {
                float acc = xh[g][i];
                acc = fmaf(w0.x, xr[g][0], acc);
                acc = fmaf(w0.y, xr[g][1], acc);
                acc = fmaf(w0.z, xr[g][2], acc);
                acc = fmaf(w0.w, xr[g][3], acc);
                acc = fmaf(w1.x, xr[g][4], acc);
                acc = fmaf(w1.y, xr[g][5], acc);
                acc = fmaf(w1.z, xr[g][6], acc);
                acc = fmaf(w1.w, xr[g][7], acc);
                xh[g][i] = acc;
            }
        }

        float c[NG];
        if (have_v) {
            float e[NG];
#pragma unroll
            for (int g = 0; g < NG; ++g) {
                float lp = 0.f;
#pragma unroll
                for (int i = 0; i < 8; ++i) lp += xh[g][i] * vc[g][i];
                float l = lp + __shfl_xor(lp, 32);   // combine i-halves
                e[g] = __expf(l);                    // |l| < 1: no max-sub
            }
            float r[NG];
#pragma unroll
            for (int g = 0; g < NG; ++g) r[g] = e[g];
#pragma unroll
            for (int d = 16; d >= 1; d >>= 1)
#pragma unroll
                for (int g = 0; g < NG; ++g) r[g] += __shfl_xor(r[g], d);
#pragma unroll
            for (int g = 0; g < NG; ++g) c[g] = e[g] / r[g];
        } else {
#pragma unroll
            for (int g = 0; g < NG; ++g) c[g] = 1.0f / 32.0f;
        }

#pragma unroll
        for (int g = 0; g < NG; ++g)
#pragma unroll
            for (int i = 0; i < 8; ++i) sacc[g][i] += c[g] * xh[g][i];
    }

    // plain float4 stores of this chunk's partial (no atomics)
    float* p = spart + (size_t)blockIdx.x * (Bb * Oo * DOv);
#pragma unroll
    for (int g = 0; g < NG; ++g) {
        float* pg = p + (((size_t)(b0 + g) * Oo + o) * DOv + ih * 8);
        ((float4*)pg)[0] = make_float4(sacc[g][0], sacc[g][1], sacc[g][2], sacc[g][3]);
        ((float4*)pg)[1] = make_float4(sacc[g][4], sacc[g][5], sacc[g][6], sacc[g][7]);
    }
}

// Reduce nch partials + squash. One wave per (b, o); float4 lanes: q = t&3, pg = t>>2.
__global__ __launch_bounds__(64) void caps_squash(
    const float* __restrict__ spart, int nch,
    const float* __restrict__ vin,   // may be nullptr (treated as 0)
    float* __restrict__ vout,        // may be nullptr
    float* __restrict__ out)         // may be nullptr
{
    const int b = blockIdx.x, oo = blockIdx.y;
    const int t = threadIdx.x;
    const int q = t & 3, pg = t >> 2;          // 16 p-groups
    const size_t base4 = ((size_t)b * Oo + oo) * (DOv / 4) + q;
    const float4* sp4 = (const float4*)spart;
    const size_t chunk4 = (size_t)Bb * Oo * DOv / 4;

    float4 s = make_float4(0.f, 0.f, 0.f, 0.f);
    for (int p = pg; p < nch; p += 16) {
        float4 v = sp4[(size_t)p * chunk4 + base4];
        s.x += v.x; s.y += v.y; s.z += v.z; s.w += v.w;
    }
#pragma unroll
    for (int d = 4; d <= 32; d <<= 1) {
        s.x += __shfl_xor(s.x, d); s.y += __shfl_xor(s.y, d);
        s.z += __shfl_xor(s.z, d); s.w += __shfl_xor(s.w, d);
    }
    float n2 = s.x * s.x + s.y * s.y + s.z * s.z + s.w * s.w;
    n2 += __shfl_xor(n2, 1);
    n2 += __shfl_xor(n2, 2);
    float sc = n2 / ((1.f + n2) * sqrtf(n2 + 1e-7f));
    if (t < 4) {
        float4 vj = make_float4(s.x * sc, s.y * sc, s.z * sc, s.w * sc);
        size_t i4 = base4;
        if (vout) {
            float4 vi = vin ? ((const float4*)vin)[i4] : make_float4(0.f, 0.f, 0.f, 0.f);
            ((float4*)vout)[i4] = make_float4(vi.x + vj.x, vi.y + vj.y, vi.z + vj.z, vi.w + vj.w);
        }
        if (out) ((float4*)out)[i4] = vj;
    }
}

extern "C" void kernel_launch(void* const* d_in, const int* in_sizes, int n_in,
                              void* d_out, int out_size, void* d_ws, size_t ws_size,
                              hipStream_t stream)
{
    const float* x = (const float*)d_in[0];
    const float* w = (const float*)d_in[1];
    float* out = (float*)d_out;

    // nch=144, NC=8 -> grid (144,4) = 576 blocks (9 waves/CU at 2/SIMD cap),
    // spart 18.9 MB.
    int nch = 144;
    size_t need = ((size_t)nch * Bb * Oo * DOv + (size_t)Bb * Oo * DOv) * sizeof(float);
    if (need > ws_size) nch = 16;    // fallback for tiny ws (NC=72)

    float* spart = (float*)d_ws;
    float* vcum  = spart + (size_t)nch * Bb * Oo * DOv;

    dim3 blk(256);
    dim3 sgrid(Bb, Oo), sblk(64);
    dim3 grid(nch, Bb / (4 * NG));

    if (nch == 144) {
        caps_route<8><<<grid, blk, 0, stream>>>(x, w, nullptr, spart);
        caps_squash<<<sgrid, sblk, 0, stream>>>(spart, nch, nullptr, vcum, nullptr);
        caps_route<8><<<grid, blk, 0, stream>>>(x, w, vcum, spart);
        caps_squash<<<sgrid, sblk, 0, stream>>>(spart, nch, vcum, vcum, nullptr);
        caps_route<8><<<grid, blk, 0, stream>>>(x, w, vcum, spart);
        caps_squash<<<sgrid, sblk, 0, stream>>>(spart, nch, nullptr, nullptr, out);
    } else {
        caps_route<72><<<grid, blk, 0, stream>>>(x, w, nullptr, spart);
        caps_squash<<<sgrid, sblk, 0, stream>>>(spart, nch, nullptr, vcum, nullptr);
        caps_route<72><<<grid, blk, 0, stream>>>(x, w, vcum, spart);
        caps_squash<<<sgrid, sblk, 0, stream>>>(spart, nch, vcum, vcum, nullptr);
        caps_route<72><<<grid, blk, 0, stream>>>(x, w, vcum, spart);
        caps_squash<<<sgrid, sblk, 0, stream>>>(spart, nch, nullptr, nullptr, out);
    }
}